// Round 17
// baseline (345.097 us; speedup 1.0000x reference)
//
#include <hip/hip_runtime.h>
#include <math.h>

#define NN    50000
#define NE    1600000
#define INDIM 2000
#define HID   8
#define SLOT  64

// ---------------- bucket fill: rec[d*SLOT+k] = {src, w} ----------------
__global__ __launch_bounds__(512) void k_fill(const int* __restrict__ src,
                                              const int* __restrict__ dst,
                                              const float* __restrict__ ew,
                                              int* __restrict__ cur,
                                              long long* __restrict__ rec, int e) {
    int i = blockIdx.x * 512 + threadIdx.x;
    if (i < e) {
        const int d = dst[i];
        const int k = atomicAdd(&cur[d], 1);
        if (k < SLOT) {
            const long long v = ((long long)__float_as_int(ew[i]) << 32) |
                                (unsigned int)src[i];
            __builtin_nontemporal_store(v, &rec[(size_t)d * SLOT + k]);
        }
    }
}

// ------- gemm + node fused (r14-exact): dinv from own rows' buckets, then gemm ----
__global__ __launch_bounds__(512) void k_gemmnode(const float* __restrict__ x,
                                                  const float* __restrict__ W1,
                                                  const int* __restrict__ cur,
                                                  const int2* __restrict__ rec,
                                                  float* __restrict__ dinv,
                                                  float* __restrict__ g1, int n) {
    __shared__ float Wt[HID][INDIM];              // 64000 B -> 2 blocks/CU
    for (int idx = threadIdx.x; idx < INDIM * HID; idx += 512)
        Wt[idx & 7][idx >> 3] = W1[idx];
    __syncthreads();

    const int lane = threadIdx.x & 63;
    const int tile = blockIdx.x * 8 + (threadIdx.x >> 6);
    if (tile >= n / 4) return;
    const int row0 = tile * 4;

    // ---- node part: dinv for rows row0..row0+3 (16 lanes per row) ----
    {
        const int r = lane >> 4, l = lane & 15;
        const int row = row0 + r;
        const int c = min(cur[row], SLOT);
        const int2* __restrict__ bkt = rec + (size_t)row * SLOT;
        float s = 0.f;
        for (int k = l; k < c; k += 16) s += __int_as_float(bkt[k].y);
        s += __shfl_xor(s, 1, 16);
        s += __shfl_xor(s, 2, 16);
        s += __shfl_xor(s, 4, 16);
        s += __shfl_xor(s, 8, 16);
        const float dv = rsqrtf(s + 1.0f);
        if (l == 0) dinv[row] = dv;

        // ---- gemm part (r9 core) ----
        const float* __restrict__ xb = &x[(size_t)row0 * INDIM];
        float acc[32];
#pragma unroll
        for (int v = 0; v < 32; ++v) acc[v] = 0.f;

        const int c0 = lane * 4;
        float4 xc[4], xn[4];
#pragma unroll
        for (int rr = 0; rr < 4; ++rr) {
            xc[rr] = make_float4(0.f, 0.f, 0.f, 0.f);
            if (c0 < INDIM) xc[rr] = *(const float4*)&xb[(size_t)rr * INDIM + c0];
        }

#pragma unroll 1
        for (int k = 0; k < 8; ++k) {
            const int cc = k * 256 + c0;
            const int cn = cc + 256;
#pragma unroll
            for (int rr = 0; rr < 4; ++rr) {
                xn[rr] = make_float4(0.f, 0.f, 0.f, 0.f);
                if (cn < INDIM) xn[rr] = *(const float4*)&xb[(size_t)rr * INDIM + cn];
            }
            if (cc < INDIM) {
#pragma unroll
                for (int j = 0; j < 8; ++j) {
                    const float4 wv = *(const float4*)&Wt[j][cc];
#pragma unroll
                    for (int rr = 0; rr < 4; ++rr)
                        acc[rr * 8 + j] += xc[rr].x * wv.x + xc[rr].y * wv.y +
                                           xc[rr].z * wv.z + xc[rr].w * wv.w;
                }
            }
#pragma unroll
            for (int rr = 0; rr < 4; ++rr) xc[rr] = xn[rr];
        }

        // multiplexed butterfly over 32 values + xor-32 merge (verified r7/r9)
#pragma unroll
        for (int st = 0; st < 5; ++st) {
            const int o = 1 << st;
            const bool hb = (lane & o) != 0;
            const int np = 32 >> (st + 1);
#pragma unroll
            for (int p = 0; p < np; ++p) {
                float v0 = acc[2 * p], v1 = acc[2 * p + 1];
                float send = hb ? v0 : v1;
                float recv = __shfl_xor(send, o);
                acc[p] = (hb ? v1 : v0) + recv;
            }
        }
        acc[0] += __shfl_xor(acc[0], 32);

        const float dvme = __shfl(dv, (lane >> 3) << 4);
        if (lane < 32)
            g1[(size_t)row0 * HID + lane] = dvme * acc[0];
    }
}

// ---------------- gather1: conv1 -> relu -> @W2 -> g2 = dinv * h2 (r9 form) ------
__global__ __launch_bounds__(512) void k_gather1(const int2* __restrict__ rec,
                                                 const int* __restrict__ cur,
                                                 const float* __restrict__ dinv,
                                                 const float* __restrict__ g1,
                                                 const float* __restrict__ b1,
                                                 const float* __restrict__ W2,
                                                 float* __restrict__ g2, int n) {
    __shared__ float sW[HID * HID];
    __shared__ float sb[HID];
    if (threadIdx.x < HID * HID) sW[threadIdx.x] = W2[threadIdx.x];
    if (threadIdx.x < HID) sb[threadIdx.x] = b1[threadIdx.x];
    __syncthreads();

    const int t = blockIdx.x * 512 + threadIdx.x;
    const int i = t >> 3, ch = t & 7;
    if (i >= n) return;

    const int c = min(cur[i], SLOT);
    const int2* __restrict__ bkt = rec + (size_t)i * SLOT;
    int2 rg[8];
#pragma unroll
    for (int j = 0; j < 8; ++j) {
        const int k = ch + 8 * j;
        rg[j] = (k < c) ? bkt[k] : make_int2(i, 0);
    }

    float acc = 0.f;
#pragma unroll
    for (int j = 0; j < 8; ++j) {
        if (8 * j < c) {
#pragma unroll
            for (int u = 0; u < 8; ++u) {
                const int   s = __shfl(rg[j].x, u, 8);
                const float w = __int_as_float(__shfl(rg[j].y, u, 8));
                acc = fmaf(w, g1[(size_t)s * HID + ch], acc);
            }
        }
    }
    acc += g1[(size_t)i * HID + ch];              // self-loop
    const float di = dinv[i];
    const float tv = fmaxf(di * acc + sb[ch], 0.f);
    float h = 0.f;
#pragma unroll
    for (int k = 0; k < HID; ++k)
        h = fmaf(__shfl(tv, k, 8), sW[k * HID + ch], h);
    g2[t] = di * h;
}

// ---------------- gather2: conv2 -> + b2 -> log_softmax -> out (r9 form) ---------
__global__ __launch_bounds__(512) void k_gather2(const int2* __restrict__ rec,
                                                 const int* __restrict__ cur,
                                                 const float* __restrict__ dinv,
                                                 const float* __restrict__ g2,
                                                 const float* __restrict__ b2,
                                                 float* __restrict__ out, int n) {
    __shared__ float sb[HID];
    if (threadIdx.x < HID) sb[threadIdx.x] = b2[threadIdx.x];
    __syncthreads();

    const int t = blockIdx.x * 512 + threadIdx.x;
    const int i = t >> 3, ch = t & 7;
    if (i >= n) return;

    const int c = min(cur[i], SLOT);
    const int2* __restrict__ bkt = rec + (size_t)i * SLOT;
    int2 rg[8];
#pragma unroll
    for (int j = 0; j < 8; ++j) {
        const int k = ch + 8 * j;
        rg[j] = (k < c) ? bkt[k] : make_int2(i, 0);
    }

    float acc = 0.f;
#pragma unroll
    for (int j = 0; j < 8; ++j) {
        if (8 * j < c) {
#pragma unroll
            for (int u = 0; u < 8; ++u) {
                const int   s = __shfl(rg[j].x, u, 8);
                const float w = __int_as_float(__shfl(rg[j].y, u, 8));
                acc = fmaf(w, g2[(size_t)s * HID + ch], acc);
            }
        }
    }
    acc += g2[(size_t)i * HID + ch];              // self-loop
    const float v = dinv[i] * acc + sb[ch];

    float m = v;
    m = fmaxf(m, __shfl_xor(m, 1, 8));
    m = fmaxf(m, __shfl_xor(m, 2, 8));
    m = fmaxf(m, __shfl_xor(m, 4, 8));
    float s = __expf(v - m);
    s += __shfl_xor(s, 1, 8);
    s += __shfl_xor(s, 2, 8);
    s += __shfl_xor(s, 4, 8);
    out[t] = v - (m + __logf(s));
}

// ---- launcher: r14 + ATTRIBUTION PROBE (k_gemmnode dispatched twice) ----
// The kernel is idempotent; Δ(total vs r14's 250µs) = one gemm dispatch's time.
extern "C" void kernel_launch(void* const* d_in, const int* in_sizes, int n_in,
                              void* d_out, int out_size, void* d_ws, size_t ws_size,
                              hipStream_t stream) {
    const float* x   = (const float*)d_in[0];
    const int*   src = (const int*)d_in[1];
    const int*   dst = (const int*)d_in[2];
    const float* ew  = (const float*)d_in[3];
    const float* W1  = (const float*)d_in[4];
    const float* b1  = (const float*)d_in[5];
    const float* W2  = (const float*)d_in[6];
    const float* b2  = (const float*)d_in[7];
    float* out = (float*)d_out;

    // workspace layout (8-B aligned first)
    long long* rec  = (long long*)d_ws;                 // NN*SLOT int2 (25.6 MB)
    int*       cur  = (int*)(rec + (size_t)NN * SLOT);  // NN
    float*     dinv = (float*)(cur + NN);               // NN
    float*     g1   = dinv + NN;                        // NN*HID
    float*     g2   = g1 + (size_t)NN * HID;            // NN*HID

    const int B = 512;
    const int gE = (NE + B - 1) / B;                    // 3125
    const int g8 = (NN * HID + B - 1) / B;              // 782
    const int gG = (NN / 4 + 7) / 8;                    // 1563

    hipMemsetAsync(cur, 0, NN * sizeof(int), stream);
    k_fill    <<<gE, B, 0, stream>>>(src, dst, ew, cur, rec, NE);
    k_gemmnode<<<gG, B, 0, stream>>>(x, W1, cur, (const int2*)rec, dinv, g1, NN);
    k_gemmnode<<<gG, B, 0, stream>>>(x, W1, cur, (const int2*)rec, dinv, g1, NN);  // probe
    k_gather1 <<<g8, B, 0, stream>>>((const int2*)rec, cur, dinv, g1, b1, W2, g2, NN);
    k_gather2 <<<g8, B, 0, stream>>>((const int2*)rec, cur, dinv, g2, b2, out, NN);
}

// Round 18
// 264.820 us; speedup vs baseline: 1.3031x; 1.3031x over previous
//
#include <hip/hip_runtime.h>
#include <math.h>

#define NN    50000
#define NE    1600000
#define INDIM 2000
#define HID   8
#define SLOT  64

// ---------------- bucket fill: rec[d*SLOT+k] = {src, w} ----------------
__global__ __launch_bounds__(512) void k_fill(const int* __restrict__ src,
                                              const int* __restrict__ dst,
                                              const float* __restrict__ ew,
                                              int* __restrict__ cur,
                                              long long* __restrict__ rec, int e) {
    int i = blockIdx.x * 512 + threadIdx.x;
    if (i < e) {
        const int d = dst[i];
        const int k = atomicAdd(&cur[d], 1);
        if (k < SLOT) {
            const long long v = ((long long)__float_as_int(ew[i]) << 32) |
                                (unsigned int)src[i];
            __builtin_nontemporal_store(v, &rec[(size_t)d * SLOT + k]);
        }
    }
}

// ------- gemm + node fused: 1024-thr block, 2 rows/wave, 32 waves/CU ----------
// W1^T staged ONCE into 64KB LDS (no mid-loop restage). launch_bounds(1024,8)
// -> 64-VGPR budget; 2-row live set ~45 regs (r8-verified, spill-proof).
// 2 blocks/CU x 16 waves = 32 waves/CU: 2x r14's wave count for latency hiding.
__global__ __launch_bounds__(1024, 8) void k_gemmnode(const float* __restrict__ x,
                                                      const float* __restrict__ W1,
                                                      const int* __restrict__ cur,
                                                      const int2* __restrict__ rec,
                                                      float* __restrict__ dinv,
                                                      float* __restrict__ g1, int n) {
    __shared__ float Wt[HID][INDIM];              // 64000 B
    for (int idx = threadIdx.x; idx < INDIM * HID; idx += 1024)
        Wt[idx & 7][idx >> 3] = W1[idx];
    __syncthreads();                              // no barriers after this point

    const int lane = threadIdx.x & 63;
    const int tile = blockIdx.x * 16 + (threadIdx.x >> 6);
    if (tile >= n / 2) return;
    const int row0 = tile * 2;

    // ---- node part: dinv for rows row0, row0+1 (32 lanes per row) ----
    const int half = lane >> 5, l = lane & 31;
    const int row = row0 + half;
    const int cdeg = min(cur[row], SLOT);
    const int2* __restrict__ bkt = rec + (size_t)row * SLOT;
    float s = 0.f;
    if (l < cdeg)      s  = __int_as_float(bkt[l].y);
    if (l + 32 < cdeg) s += __int_as_float(bkt[l + 32].y);
    s += __shfl_xor(s, 1, 32);
    s += __shfl_xor(s, 2, 32);
    s += __shfl_xor(s, 4, 32);
    s += __shfl_xor(s, 8, 32);
    s += __shfl_xor(s, 16, 32);
    const float dv = rsqrtf(s + 1.0f);
    if (l == 0) dinv[row] = dv;

    // ---- gemm part: 2 rows/wave, rolled k-loop + depth-1 prefetch (r8 core) ----
    const float* __restrict__ xr0 = &x[(size_t)row0 * INDIM];
    const float* __restrict__ xr1 = xr0 + INDIM;

    float acc[16];
#pragma unroll
    for (int v = 0; v < 16; ++v) acc[v] = 0.f;

    const int c0 = lane * 4;
    float4 xc0 = make_float4(0.f, 0.f, 0.f, 0.f), xc1 = xc0;
    if (c0 < INDIM) {
        xc0 = *(const float4*)&xr0[c0];
        xc1 = *(const float4*)&xr1[c0];
    }

#pragma unroll 1
    for (int k = 0; k < 8; ++k) {
        const int c  = k * 256 + c0;
        const int cn = c + 256;
        float4 xn0 = make_float4(0.f, 0.f, 0.f, 0.f), xn1 = xn0;
        if (cn < INDIM) {
            xn0 = *(const float4*)&xr0[cn];
            xn1 = *(const float4*)&xr1[cn];
        }
        if (c < INDIM) {
#pragma unroll
            for (int j = 0; j < 8; ++j) {
                const float4 wv = *(const float4*)&Wt[j][c];
                acc[j]     += xc0.x * wv.x + xc0.y * wv.y + xc0.z * wv.z + xc0.w * wv.w;
                acc[8 + j] += xc1.x * wv.x + xc1.y * wv.y + xc1.z * wv.z + xc1.w * wv.w;
            }
        }
        xc0 = xn0; xc1 = xn1;
    }

    // multiplexed butterfly over 16 values + xor-16/32 merges (verified r8)
#pragma unroll
    for (int st = 0; st < 4; ++st) {
        const int o = 1 << st;
        const bool hb = (lane & o) != 0;
        const int np = 16 >> (st + 1);
#pragma unroll
        for (int p = 0; p < np; ++p) {
            float v0 = acc[2 * p], v1 = acc[2 * p + 1];
            float send = hb ? v0 : v1;
            float recv = __shfl_xor(send, o);
            acc[p] = (hb ? v1 : v0) + recv;
        }
    }
    acc[0] += __shfl_xor(acc[0], 16);
    acc[0] += __shfl_xor(acc[0], 32);

    // lane<16 owns value v=lane: row = row0+(lane>>3), ch = lane&7.
    // dv for row0 lives in lanes 0-31, for row0+1 in lanes 32-63.
    const float dvme = __shfl(dv, (lane & 8) << 2);
    if (lane < 16)
        g1[(size_t)row0 * HID + lane] = dvme * acc[0];
}

// ---------------- gather1: conv1 -> relu -> @W2 -> g2 = dinv * h2 (r9 form) ------
__global__ __launch_bounds__(512) void k_gather1(const int2* __restrict__ rec,
                                                 const int* __restrict__ cur,
                                                 const float* __restrict__ dinv,
                                                 const float* __restrict__ g1,
                                                 const float* __restrict__ b1,
                                                 const float* __restrict__ W2,
                                                 float* __restrict__ g2, int n) {
    __shared__ float sW[HID * HID];
    __shared__ float sb[HID];
    if (threadIdx.x < HID * HID) sW[threadIdx.x] = W2[threadIdx.x];
    if (threadIdx.x < HID) sb[threadIdx.x] = b1[threadIdx.x];
    __syncthreads();

    const int t = blockIdx.x * 512 + threadIdx.x;
    const int i = t >> 3, ch = t & 7;
    if (i >= n) return;

    const int c = min(cur[i], SLOT);
    const int2* __restrict__ bkt = rec + (size_t)i * SLOT;
    int2 rg[8];
#pragma unroll
    for (int j = 0; j < 8; ++j) {
        const int k = ch + 8 * j;
        rg[j] = (k < c) ? bkt[k] : make_int2(i, 0);
    }

    float acc = 0.f;
#pragma unroll
    for (int j = 0; j < 8; ++j) {
        if (8 * j < c) {
#pragma unroll
            for (int u = 0; u < 8; ++u) {
                const int   s = __shfl(rg[j].x, u, 8);
                const float w = __int_as_float(__shfl(rg[j].y, u, 8));
                acc = fmaf(w, g1[(size_t)s * HID + ch], acc);
            }
        }
    }
    acc += g1[(size_t)i * HID + ch];              // self-loop
    const float di = dinv[i];
    const float tv = fmaxf(di * acc + sb[ch], 0.f);
    float h = 0.f;
#pragma unroll
    for (int k = 0; k < HID; ++k)
        h = fmaf(__shfl(tv, k, 8), sW[k * HID + ch], h);
    g2[t] = di * h;
}

// ---------------- gather2: conv2 -> + b2 -> log_softmax -> out (r9 form) ---------
__global__ __launch_bounds__(512) void k_gather2(const int2* __restrict__ rec,
                                                 const int* __restrict__ cur,
                                                 const float* __restrict__ dinv,
                                                 const float* __restrict__ g2,
                                                 const float* __restrict__ b2,
                                                 float* __restrict__ out, int n) {
    __shared__ float sb[HID];
    if (threadIdx.x < HID) sb[threadIdx.x] = b2[threadIdx.x];
    __syncthreads();

    const int t = blockIdx.x * 512 + threadIdx.x;
    const int i = t >> 3, ch = t & 7;
    if (i >= n) return;

    const int c = min(cur[i], SLOT);
    const int2* __restrict__ bkt = rec + (size_t)i * SLOT;
    int2 rg[8];
#pragma unroll
    for (int j = 0; j < 8; ++j) {
        const int k = ch + 8 * j;
        rg[j] = (k < c) ? bkt[k] : make_int2(i, 0);
    }

    float acc = 0.f;
#pragma unroll
    for (int j = 0; j < 8; ++j) {
        if (8 * j < c) {
#pragma unroll
            for (int u = 0; u < 8; ++u) {
                const int   s = __shfl(rg[j].x, u, 8);
                const float w = __int_as_float(__shfl(rg[j].y, u, 8));
                acc = fmaf(w, g2[(size_t)s * HID + ch], acc);
            }
        }
    }
    acc += g2[(size_t)i * HID + ch];              // self-loop
    const float v = dinv[i] * acc + sb[ch];

    float m = v;
    m = fmaxf(m, __shfl_xor(m, 1, 8));
    m = fmaxf(m, __shfl_xor(m, 2, 8));
    m = fmaxf(m, __shfl_xor(m, 4, 8));
    float s = __expf(v - m);
    s += __shfl_xor(s, 1, 8);
    s += __shfl_xor(s, 2, 8);
    s += __shfl_xor(s, 4, 8);
    out[t] = v - (m + __logf(s));
}

// ---------------- launcher: 5 dispatches (memset + 4 kernels) ----------------
extern "C" void kernel_launch(void* const* d_in, const int* in_sizes, int n_in,
                              void* d_out, int out_size, void* d_ws, size_t ws_size,
                              hipStream_t stream) {
    const float* x   = (const float*)d_in[0];
    const int*   src = (const int*)d_in[1];
    const int*   dst = (const int*)d_in[2];
    const float* ew  = (const float*)d_in[3];
    const float* W1  = (const float*)d_in[4];
    const float* b1  = (const float*)d_in[5];
    const float* W2  = (const float*)d_in[6];
    const float* b2  = (const float*)d_in[7];
    float* out = (float*)d_out;

    // workspace layout (8-B aligned first)
    long long* rec  = (long long*)d_ws;                 // NN*SLOT int2 (25.6 MB)
    int*       cur  = (int*)(rec + (size_t)NN * SLOT);  // NN
    float*     dinv = (float*)(cur + NN);               // NN
    float*     g1   = dinv + NN;                        // NN*HID
    float*     g2   = g1 + (size_t)NN * HID;            // NN*HID

    const int B = 512;
    const int gE = (NE + B - 1) / B;                    // 3125
    const int g8 = (NN * HID + B - 1) / B;              // 782
    const int gG = (NN / 2 + 15) / 16;                  // 1563 (2 rows/wave, 16 waves/blk)

    hipMemsetAsync(cur, 0, NN * sizeof(int), stream);
    k_fill    <<<gE, B, 0, stream>>>(src, dst, ew, cur, rec, NE);
    k_gemmnode<<<gG, 1024, 0, stream>>>(x, W1, cur, (const int2*)rec, dinv, g1, NN);
    k_gather1 <<<g8, B, 0, stream>>>((const int2*)rec, cur, dinv, g1, b1, W2, g2, NN);
    k_gather2 <<<g8, B, 0, stream>>>((const int2*)rec, cur, dinv, g2, b2, out, NN);
}